// Round 1
// baseline (1049.880 us; speedup 1.0000x reference)
//
#include <hip/hip_runtime.h>
#include <math.h>

#define HDIM 128
#define TDIM 4096
#define NET_T 8

// ---------------------------------------------------------------------------
// helpers
// ---------------------------------------------------------------------------
__device__ __forceinline__ float wave_sum64(float v) {
#pragma unroll
  for (int d = 32; d > 0; d >>= 1) v += __shfl_xor(v, d, 64);
  return v;
}

__device__ __forceinline__ float gelu_exact(float x) {
  return 0.5f * x * (1.0f + erff(x * 0.70710678118654752440f));
}

struct LN2 { float zx, zy, norm; };

// layer-norm over 128 elements spread 2-per-lane across one 64-lane wave.
// biased variance, eps=1e-5, no affine. norm = ||z||_2 (uniform across lanes).
__device__ __forceinline__ LN2 ln128(float x0, float x1) {
  float s = wave_sum64(x0 + x1);
  float mean = s * (1.0f / 128.0f);
  float d0 = x0 - mean, d1 = x1 - mean;
  float sq = wave_sum64(d0 * d0 + d1 * d1);
  float var = sq * (1.0f / 128.0f);
  float rstd = rsqrtf(var + 1e-5f);
  LN2 r;
  r.zx = d0 * rstd;
  r.zy = d1 * rstd;
  r.norm = sqrtf(sq) * rstd;   // sqrt(sum z^2) = sqrt(sq)*rstd
  return r;
}

// ---------------------------------------------------------------------------
// K1: per-subgraph counts (target edges; all nodes)
// ---------------------------------------------------------------------------
__global__ void count_kernel(const int* __restrict__ edge_dst,
                             const int* __restrict__ esg,
                             const int* __restrict__ tli,
                             const int* __restrict__ nsg,
                             int* __restrict__ ecnt, int* __restrict__ ncnt,
                             int E_, int N_) {
  int gid = blockIdx.x * blockDim.x + threadIdx.x;
  if (gid < E_) {
    int s = esg[gid];
    if (edge_dst[gid] == tli[s]) atomicAdd(&ecnt[s], 1);
  }
  if (gid < N_) {
    atomicAdd(&ncnt[nsg[gid]], 1);
  }
}

// ---------------------------------------------------------------------------
// K2: exclusive scan of 4096 counts. One 64-lane wave per array.
// block 0 -> edge counts, block 1 -> node counts.
// ---------------------------------------------------------------------------
__global__ __launch_bounds__(64) void scan_kernel(
    const int* __restrict__ ecnt, int* __restrict__ eoff, int* __restrict__ ecur,
    const int* __restrict__ ncnt, int* __restrict__ noff, int* __restrict__ ncur) {
  const int* cnt;
  int *off, *cur;
  if (blockIdx.x == 0) { cnt = ecnt; off = eoff; cur = ecur; }
  else                 { cnt = ncnt; off = noff; cur = ncur; }
  int lane = threadIdx.x;
  int base = lane * 64;
  int s = 0;
  for (int i = 0; i < 64; i++) s += cnt[base + i];
  int incl = s;
#pragma unroll
  for (int d = 1; d < 64; d <<= 1) {
    int v = __shfl_up(incl, d, 64);
    if (lane >= d) incl += v;
  }
  int run = incl - s;  // exclusive prefix over chunks
  for (int i = 0; i < 64; i++) {
    off[base + i] = run;
    cur[base + i] = run;
    run += cnt[base + i];
  }
}

// ---------------------------------------------------------------------------
// K3: scatter target-edge records and node records into per-subgraph buckets
// ---------------------------------------------------------------------------
__global__ void scatter_kernel(const int* __restrict__ edge_dst,
                               const int* __restrict__ esg,
                               const int* __restrict__ tli,
                               const int* __restrict__ edge_src,
                               const int* __restrict__ rel_ids,
                               const float* __restrict__ etime,
                               const int* __restrict__ nsg,
                               const int* __restrict__ depth,
                               int* __restrict__ ecur, int* __restrict__ ncur,
                               int* __restrict__ s_eid, int* __restrict__ s_srcpk,
                               float* __restrict__ s_t, int* __restrict__ s_npk,
                               int E_, int N_) {
  int gid = blockIdx.x * blockDim.x + threadIdx.x;
  if (gid < E_) {
    int sg = esg[gid];
    if (edge_dst[gid] == tli[sg]) {
      int pos = atomicAdd(&ecur[sg], 1);
      s_eid[pos] = gid;
      s_srcpk[pos] = (edge_src[gid] << 1) | (rel_ids[gid] < NET_T ? 1 : 0);
      s_t[pos] = etime[gid];
    }
  }
  if (gid < N_) {
    int sg = nsg[gid];
    int pos = atomicAdd(&ncur[sg], 1);
    s_npk[pos] = (gid << 1) | (depth[gid] == 1 ? 1 : 0);
  }
}

// ---------------------------------------------------------------------------
// K4: one wave (64 threads) per target. Each lane owns columns 2*lane, 2*lane+1.
// Accumulates all weighted segment sums in registers, does 8 layer-norms via
// wave shuffles, writes fused input row [1056] and atomic norm sums.
// ---------------------------------------------------------------------------
__global__ __launch_bounds__(64) void target_kernel(
    const float* __restrict__ node_repr, const float* __restrict__ edge_repr,
    const int* __restrict__ eoff, const int* __restrict__ ecnt,
    const int* __restrict__ noff, const int* __restrict__ ncnt,
    const int* __restrict__ s_eid, const int* __restrict__ s_srcpk,
    const float* __restrict__ s_t, const int* __restrict__ s_npk,
    const float* __restrict__ W1, const float* __restrict__ b1,
    float* __restrict__ fused, float* __restrict__ norm_acc) {
  const int t = blockIdx.x;
  const int lane = threadIdx.x;
  const int e0 = eoff[t], ec = ecnt[t];
  const int n0 = noff[t], nc = ncnt[t];

  // edge-side accumulators (2 columns per lane)
  float ais0 = 0, ais1 = 0, aos0 = 0, aos1 = 0;
  float ail0 = 0, ail1 = 0, aol0 = 0, aol1 = 0;
  float hs0 = 0, hs1 = 0, hl0 = 0, hl1 = 0;
  float d_is = 0, d_os = 0, d_il = 0, d_ol = 0, tsum = 0, cin = 0;

  for (int i = e0; i < e0 + ec; i++) {
    int eid = s_eid[i];
    int pk = s_srcpk[i];
    float tt = s_t[i];
    float sw = expf(-tt);
    float lw = expf(-tt * (1.0f / 24.0f));
    float fin = (float)(pk & 1);
    int src = pk >> 1;
    const float2 er = *(const float2*)(edge_repr + (size_t)eid * HDIM + 2 * lane);
    const float2 nr = *(const float2*)(node_repr + (size_t)src * HDIM + 2 * lane);
    float wis = fin * sw, wos = sw - wis;
    float wil = fin * lw, wol = lw - wil;
    ais0 += er.x * wis; ais1 += er.y * wis;
    aos0 += er.x * wos; aos1 += er.y * wos;
    ail0 += er.x * wil; ail1 += er.y * wil;
    aol0 += er.x * wol; aol1 += er.y * wol;
    hs0 += nr.x * sw; hs1 += nr.y * sw;
    hl0 += nr.x * lw; hl1 += nr.y * lw;
    d_is += wis; d_os += wos; d_il += wil; d_ol += wol;
    tsum += tt; cin += fin;
  }

  // node-side accumulators
  float h10 = 0, h11 = 0, h20 = 0, h21 = 0, c1 = 0;
  for (int i = n0; i < n0 + nc; i++) {
    int pk = s_npk[i];
    float f1 = (float)(pk & 1);
    int idx = pk >> 1;
    const float2 nr = *(const float2*)(node_repr + (size_t)idx * HDIM + 2 * lane);
    h10 += nr.x * f1;           h11 += nr.y * f1;
    h20 += nr.x * (1.0f - f1);  h21 += nr.y * (1.0f - f1);
    c1 += f1;
  }
  float c2 = (float)nc - c1;

  // weighted means (num / max(den,1e-6))
  float r_is = 1.0f / fmaxf(d_is, 1e-6f);
  float r_os = 1.0f / fmaxf(d_os, 1e-6f);
  float r_il = 1.0f / fmaxf(d_il, 1e-6f);
  float r_ol = 1.0f / fmaxf(d_ol, 1e-6f);
  float sm = d_is + d_os;  // short_mass
  float lm = d_il + d_ol;  // long_mass
  float r_sm = 1.0f / fmaxf(sm, 1e-6f);
  float r_lm = 1.0f / fmaxf(lm, 1e-6f);
  float r_c1 = 1.0f / fmaxf(c1, 1e-6f);
  float r_c2 = 1.0f / fmaxf(c2, 1e-6f);

  float mis0 = ais0 * r_is, mis1 = ais1 * r_is;
  float mos0 = aos0 * r_os, mos1 = aos1 * r_os;
  float mil0 = ail0 * r_il, mil1 = ail1 * r_il;
  float mol0 = aol0 * r_ol, mol1 = aol1 * r_ol;
  float mhs0 = hs0 * r_sm, mhs1 = hs1 * r_sm;
  float mhl0 = hl0 * r_lm, mhl1 = hl1 * r_lm;
  float mh10 = h10 * r_c1, mh11 = h11 * r_c1;
  float mh20 = h20 * r_c2, mh21 = h21 * r_c2;

  // 8 layer-normed features
  LN2 z_burst = ln128(mis0 + mos0 - mil0 - mol0, mis1 + mos1 - mil1 - mol1);
  LN2 z_dgap  = ln128(mol0 - mil0, mol1 - mil1);
  LN2 z_hgap  = ln128(mh10 - mh20, mh11 - mh21);
  LN2 z_sl    = ln128(mhs0 - mhl0, mhs1 - mhl1);
  LN2 z_asym  = ln128(fabsf(z_dgap.zx), fabsf(z_dgap.zy));
  LN2 z_h1    = ln128(mh10, mh11);
  LN2 z_h2    = ln128(mh20, mh21);
  LN2 z_rb    = ln128(mil0 + mol0, mil1 + mol1);

  if (lane == 0) {
    atomicAdd(&norm_acc[0], z_hgap.norm);
    atomicAdd(&norm_acc[1], z_sl.norm);
    atomicAdd(&norm_acc[2], z_dgap.norm);
  }

  float* frow = fused + (size_t)t * 1056;
  int co = 2 * lane;
  *(float2*)(frow + 0 * HDIM + co) = make_float2(z_burst.zx, z_burst.zy);
  *(float2*)(frow + 1 * HDIM + co) = make_float2(z_dgap.zx, z_dgap.zy);
  *(float2*)(frow + 2 * HDIM + co) = make_float2(z_hgap.zx, z_hgap.zy);
  *(float2*)(frow + 3 * HDIM + co) = make_float2(z_sl.zx, z_sl.zy);
  *(float2*)(frow + 4 * HDIM + co) = make_float2(z_asym.zx, z_asym.zy);
  *(float2*)(frow + 5 * HDIM + co) = make_float2(z_h1.zx, z_h1.zy);
  *(float2*)(frow + 6 * HDIM + co) = make_float2(z_h2.zx, z_h2.zy);
  *(float2*)(frow + 7 * HDIM + co) = make_float2(z_rb.zx, z_rb.zy);

  // scalar features -> Linear(8,32) -> exact GELU
  float ecf = (float)ec;
  float sf[8];
  sf[0] = log1pf(cin);
  sf[1] = log1pf(ecf - cin);
  sf[2] = log1pf(c1);
  sf[3] = log1pf(c2);
  sf[4] = tsum / fmaxf(ecf, 1e-6f);
  sf[5] = sm;
  sf[6] = lm;
  sf[7] = sm - lm;
  if (lane < 32) {
    float acc = b1[lane];
#pragma unroll
    for (int i = 0; i < 8; i++) acc += sf[i] * W1[i * 32 + lane];
    frow[1024 + lane] = gelu_exact(acc);
  }
}

// ---------------------------------------------------------------------------
// K5/K6: tiled fp32 GEMM  C[M,N] = epilogue(A[M,K] @ B[K,N] + bias)
// 64x64 tile, BK=32, 256 threads, 4x4 per-thread microtile.
// MODE 0: exact GELU (hidden). MODE 1: 0.25*tanh (risk embedding).
// M,K,N all multiples of tile sizes for our shapes.
// ---------------------------------------------------------------------------
template <int MODE>
__global__ __launch_bounds__(256) void gemm_kernel(
    const float* __restrict__ A, const float* __restrict__ B,
    const float* __restrict__ bias, float* __restrict__ C,
    int M, int N, int K) {
  __shared__ __align__(16) float As[32][68];  // A^T tile: [k][m]
  __shared__ __align__(16) float Bs[32][68];  // B tile:   [k][n]
  const int tid = threadIdx.x;
  const int tx = tid & 15, ty = tid >> 4;
  const int m0 = blockIdx.y * 64, n0 = blockIdx.x * 64;
  float acc[4][4] = {};

  for (int kt = 0; kt < K; kt += 32) {
#pragma unroll
    for (int i = 0; i < 8; i++) {
      int idx = i * 256 + tid;
      int m = idx >> 5, k = idx & 31;
      As[k][m] = A[(size_t)(m0 + m) * K + kt + k];
      int kb = idx >> 6, n = idx & 63;
      Bs[kb][n] = B[(size_t)(kt + kb) * N + n0 + n];
    }
    __syncthreads();
#pragma unroll
    for (int kk = 0; kk < 32; kk++) {
      float4 a4 = *(const float4*)&As[kk][ty * 4];
      float4 b4 = *(const float4*)&Bs[kk][tx * 4];
      float a[4] = {a4.x, a4.y, a4.z, a4.w};
      float b[4] = {b4.x, b4.y, b4.z, b4.w};
#pragma unroll
      for (int i2 = 0; i2 < 4; i2++)
#pragma unroll
        for (int j2 = 0; j2 < 4; j2++)
          acc[i2][j2] = fmaf(a[i2], b[j2], acc[i2][j2]);
    }
    __syncthreads();
  }

#pragma unroll
  for (int i2 = 0; i2 < 4; i2++) {
    int m = m0 + ty * 4 + i2;
#pragma unroll
    for (int j2 = 0; j2 < 4; j2++) {
      int n = n0 + tx * 4 + j2;
      float v = acc[i2][j2] + bias[n];
      if (MODE == 0) v = gelu_exact(v);
      else           v = 0.25f * tanhf(v);
      C[(size_t)m * N + n] = v;
    }
  }
}

// ---------------------------------------------------------------------------
// K7: norms -> output tail
// ---------------------------------------------------------------------------
__global__ void finalize_kernel(const float* __restrict__ norm_acc,
                                float* __restrict__ out) {
  int i = threadIdx.x;
  if (i < 3) out[(size_t)TDIM * HDIM + i] = norm_acc[i] * (1.0f / (float)TDIM);
}

// ---------------------------------------------------------------------------
extern "C" void kernel_launch(void* const* d_in, const int* in_sizes, int n_in,
                              void* d_out, int out_size, void* d_ws, size_t ws_size,
                              hipStream_t stream) {
  const float* node_repr = (const float*)d_in[0];
  const float* edge_repr = (const float*)d_in[1];
  const int* edge_src = (const int*)d_in[2];
  const int* edge_dst = (const int*)d_in[3];
  const int* rel_ids = (const int*)d_in[4];
  const float* etime = (const float*)d_in[5];
  const int* tli = (const int*)d_in[6];
  const int* nsg = (const int*)d_in[7];
  const int* esg = (const int*)d_in[8];
  const int* depth = (const int*)d_in[9];
  const float* W1 = (const float*)d_in[10];
  const float* b1 = (const float*)d_in[11];
  const float* W2 = (const float*)d_in[12];
  const float* b2 = (const float*)d_in[13];
  const float* W3 = (const float*)d_in[14];
  const float* b3 = (const float*)d_in[15];
  float* out = (float*)d_out;

  const int E_ = in_sizes[2];
  const int N_ = in_sizes[7];

  char* ws = (char*)d_ws;
  size_t off = 0;
  auto alloc = [&](size_t bytes) -> void* {
    off = (off + 255) & ~(size_t)255;
    void* p = ws + off;
    off += bytes;
    return p;
  };
  int* ecnt = (int*)alloc((size_t)TDIM * 4);
  int* eoff = (int*)alloc((size_t)TDIM * 4);
  int* ecur = (int*)alloc((size_t)TDIM * 4);
  int* ncnt = (int*)alloc((size_t)TDIM * 4);
  int* noff = (int*)alloc((size_t)TDIM * 4);
  int* ncur = (int*)alloc((size_t)TDIM * 4);
  int* s_eid = (int*)alloc((size_t)E_ * 4);
  int* s_srcpk = (int*)alloc((size_t)E_ * 4);
  float* s_t = (float*)alloc((size_t)E_ * 4);
  int* s_npk = (int*)alloc((size_t)N_ * 4);
  float* fused = (float*)alloc((size_t)TDIM * 1056 * 4);
  float* hidden = (float*)alloc((size_t)TDIM * 256 * 4);
  float* norm_acc = (float*)alloc(4 * 4);

  hipMemsetAsync(ecnt, 0, (size_t)TDIM * 4, stream);
  hipMemsetAsync(ncnt, 0, (size_t)TDIM * 4, stream);
  hipMemsetAsync(norm_acc, 0, 16, stream);

  int gmax = (E_ > N_ ? E_ : N_);
  int g1 = (gmax + 255) / 256;

  count_kernel<<<g1, 256, 0, stream>>>(edge_dst, esg, tli, nsg, ecnt, ncnt, E_, N_);
  scan_kernel<<<2, 64, 0, stream>>>(ecnt, eoff, ecur, ncnt, noff, ncur);
  scatter_kernel<<<g1, 256, 0, stream>>>(edge_dst, esg, tli, edge_src, rel_ids,
                                         etime, nsg, depth, ecur, ncur,
                                         s_eid, s_srcpk, s_t, s_npk, E_, N_);
  target_kernel<<<TDIM, 64, 0, stream>>>(node_repr, edge_repr, eoff, ecnt, noff,
                                         ncnt, s_eid, s_srcpk, s_t, s_npk,
                                         W1, b1, fused, norm_acc);
  gemm_kernel<0><<<dim3(256 / 64, TDIM / 64), 256, 0, stream>>>(
      fused, W2, b2, hidden, TDIM, 256, 8 * HDIM + 32);
  gemm_kernel<1><<<dim3(HDIM / 64, TDIM / 64), 256, 0, stream>>>(
      hidden, W3, b3, out, TDIM, HDIM, 256);
  finalize_kernel<<<1, 64, 0, stream>>>(norm_acc, out);
}

// Round 2
// 988.418 us; speedup vs baseline: 1.0622x; 1.0622x over previous
//
#include <hip/hip_runtime.h>
#include <math.h>

#define HDIM 128
#define TDIM 4096
#define NET_T 8

// ---------------------------------------------------------------------------
// helpers
// ---------------------------------------------------------------------------
__device__ __forceinline__ float wave_sum64(float v) {
#pragma unroll
  for (int d = 32; d > 0; d >>= 1) v += __shfl_xor(v, d, 64);
  return v;
}

__device__ __forceinline__ float gelu_exact(float x) {
  return 0.5f * x * (1.0f + erff(x * 0.70710678118654752440f));
}

struct LN2 { float zx, zy, norm; };

// layer-norm over 128 elements spread 2-per-lane across one 64-lane wave.
// biased variance, eps=1e-5, no affine. norm = ||z||_2 (uniform across lanes).
__device__ __forceinline__ LN2 ln128(float x0, float x1) {
  float s = wave_sum64(x0 + x1);
  float mean = s * (1.0f / 128.0f);
  float d0 = x0 - mean, d1 = x1 - mean;
  float sq = wave_sum64(d0 * d0 + d1 * d1);
  float var = sq * (1.0f / 128.0f);
  float rstd = rsqrtf(var + 1e-5f);
  LN2 r;
  r.zx = d0 * rstd;
  r.zy = d1 * rstd;
  r.norm = sqrtf(sq) * rstd;
  return r;
}

// ---------------------------------------------------------------------------
// K1: per-subgraph counts (target edges; all nodes)
// ---------------------------------------------------------------------------
__global__ void count_kernel(const int* __restrict__ edge_dst,
                             const int* __restrict__ esg,
                             const int* __restrict__ tli,
                             const int* __restrict__ nsg,
                             int* __restrict__ ecnt, int* __restrict__ ncnt,
                             int E_, int N_) {
  int gid = blockIdx.x * blockDim.x + threadIdx.x;
  if (gid < E_) {
    int s = esg[gid];
    if (edge_dst[gid] == tli[s]) atomicAdd(&ecnt[s], 1);
  }
  if (gid < N_) {
    atomicAdd(&ncnt[nsg[gid]], 1);
  }
}

// ---------------------------------------------------------------------------
// K2: exclusive scan of 4096 counts. One 64-lane wave per array.
// ---------------------------------------------------------------------------
__global__ __launch_bounds__(64) void scan_kernel(
    const int* __restrict__ ecnt, int* __restrict__ eoff, int* __restrict__ ecur,
    const int* __restrict__ ncnt, int* __restrict__ noff, int* __restrict__ ncur) {
  const int* cnt;
  int *off, *cur;
  if (blockIdx.x == 0) { cnt = ecnt; off = eoff; cur = ecur; }
  else                 { cnt = ncnt; off = noff; cur = ncur; }
  int lane = threadIdx.x;
  int base = lane * 64;
  int s = 0;
  for (int i = 0; i < 64; i++) s += cnt[base + i];
  int incl = s;
#pragma unroll
  for (int d = 1; d < 64; d <<= 1) {
    int v = __shfl_up(incl, d, 64);
    if (lane >= d) incl += v;
  }
  int run = incl - s;
  for (int i = 0; i < 64; i++) {
    off[base + i] = run;
    cur[base + i] = run;
    run += cnt[base + i];
  }
}

// ---------------------------------------------------------------------------
// K3: scatter target-edge records and node records into per-subgraph buckets
// ---------------------------------------------------------------------------
__global__ void scatter_kernel(const int* __restrict__ edge_dst,
                               const int* __restrict__ esg,
                               const int* __restrict__ tli,
                               const int* __restrict__ edge_src,
                               const int* __restrict__ rel_ids,
                               const float* __restrict__ etime,
                               const int* __restrict__ nsg,
                               const int* __restrict__ depth,
                               int* __restrict__ ecur, int* __restrict__ ncur,
                               int* __restrict__ s_eid, int* __restrict__ s_srcpk,
                               float* __restrict__ s_t, int* __restrict__ s_npk,
                               int E_, int N_) {
  int gid = blockIdx.x * blockDim.x + threadIdx.x;
  if (gid < E_) {
    int sg = esg[gid];
    if (edge_dst[gid] == tli[sg]) {
      int pos = atomicAdd(&ecur[sg], 1);
      s_eid[pos] = gid;
      s_srcpk[pos] = (edge_src[gid] << 1) | (rel_ids[gid] < NET_T ? 1 : 0);
      s_t[pos] = etime[gid];
    }
  }
  if (gid < N_) {
    int sg = nsg[gid];
    int pos = atomicAdd(&ncur[sg], 1);
    s_npk[pos] = (gid << 1) | (depth[gid] == 1 ? 1 : 0);
  }
}

// ---------------------------------------------------------------------------
// K4: 4 waves (256 threads) per target.
//   waves 0,1: edge list (interleaved halves), waves 2,3: node list.
//   Partials -> LDS, wave 0 combines, does 8 layer-norms + epilogue.
// Each lane owns columns 2*lane, 2*lane+1 of H=128.
// ---------------------------------------------------------------------------
__global__ __launch_bounds__(256) void target_kernel(
    const float* __restrict__ node_repr, const float* __restrict__ edge_repr,
    const int* __restrict__ eoff, const int* __restrict__ ecnt,
    const int* __restrict__ noff, const int* __restrict__ ncnt,
    const int* __restrict__ s_eid, const int* __restrict__ s_srcpk,
    const float* __restrict__ s_t, const int* __restrict__ s_npk,
    const float* __restrict__ W1, const float* __restrict__ b1,
    float* __restrict__ fused, float* __restrict__ norm_acc) {
  const int t = blockIdx.x;
  const int tid = threadIdx.x;
  const int w = tid >> 6;
  const int lane = tid & 63;
  const int e0 = eoff[t], ec = ecnt[t];
  const int n0 = noff[t], nc = ncnt[t];

  // LDS combine buffers
  __shared__ float lse[2][6][128];  // per edge-wave: ais, aos, ail, aol, hs, hl
  __shared__ float lss[2][6];       // per edge-wave: d_is,d_os,d_il,d_ol,tsum,cin
  __shared__ float lsn[2][2][128];  // per node-wave: h1, h2
  __shared__ float lnc[2];          // per node-wave: c1

  const int co = 2 * lane;

  if (w < 2) {
    // ---- edge waves ----
    float ais0 = 0, ais1 = 0, aos0 = 0, aos1 = 0;
    float ail0 = 0, ail1 = 0, aol0 = 0, aol1 = 0;
    float hs0 = 0, hs1 = 0, hl0 = 0, hl1 = 0;
    float d_is = 0, d_os = 0, d_il = 0, d_ol = 0, tsum = 0, cin = 0;

#define EDGE_BODY(ii)                                                          \
    {                                                                          \
      int eid = s_eid[ii];                                                     \
      int pk = s_srcpk[ii];                                                    \
      float tt = s_t[ii];                                                      \
      int src = pk >> 1;                                                       \
      const float2 er = *(const float2*)(edge_repr + (size_t)eid * HDIM + co);\
      const float2 nr = *(const float2*)(node_repr + (size_t)src * HDIM + co);\
      float sw = expf(-tt);                                                    \
      float lw = expf(-tt * (1.0f / 24.0f));                                   \
      float fin = (float)(pk & 1);                                             \
      float wis = fin * sw, wos = sw - wis;                                    \
      float wil = fin * lw, wol = lw - wil;                                    \
      ais0 += er.x * wis; ais1 += er.y * wis;                                  \
      aos0 += er.x * wos; aos1 += er.y * wos;                                  \
      ail0 += er.x * wil; ail1 += er.y * wil;                                  \
      aol0 += er.x * wol; aol1 += er.y * wol;                                  \
      hs0 += nr.x * sw; hs1 += nr.y * sw;                                      \
      hl0 += nr.x * lw; hl1 += nr.y * lw;                                      \
      d_is += wis; d_os += wos; d_il += wil; d_ol += wol;                      \
      tsum += tt; cin += fin;                                                  \
    }

    int i = e0 + w;
    const int end = e0 + ec;
    for (; i + 2 < end; i += 4) { EDGE_BODY(i); EDGE_BODY(i + 2); }
    if (i < end) EDGE_BODY(i);
#undef EDGE_BODY

    lse[w][0][co] = ais0; lse[w][0][co + 1] = ais1;
    lse[w][1][co] = aos0; lse[w][1][co + 1] = aos1;
    lse[w][2][co] = ail0; lse[w][2][co + 1] = ail1;
    lse[w][3][co] = aol0; lse[w][3][co + 1] = aol1;
    lse[w][4][co] = hs0;  lse[w][4][co + 1] = hs1;
    lse[w][5][co] = hl0;  lse[w][5][co + 1] = hl1;
    if (lane == 0) {
      lss[w][0] = d_is; lss[w][1] = d_os; lss[w][2] = d_il;
      lss[w][3] = d_ol; lss[w][4] = tsum; lss[w][5] = cin;
    }
  } else {
    // ---- node waves ----
    const int w2 = w - 2;
    float h10 = 0, h11 = 0, h20 = 0, h21 = 0, c1 = 0;

#define NODE_BODY(ii)                                                          \
    {                                                                          \
      int pk = s_npk[ii];                                                      \
      int idx = pk >> 1;                                                       \
      const float2 nr = *(const float2*)(node_repr + (size_t)idx * HDIM + co);\
      float f1 = (float)(pk & 1);                                              \
      h10 += nr.x * f1;          h11 += nr.y * f1;                             \
      h20 += nr.x * (1.0f - f1); h21 += nr.y * (1.0f - f1);                    \
      c1 += f1;                                                                \
    }

    int i = n0 + w2;
    const int end = n0 + nc;
    for (; i + 2 < end; i += 4) { NODE_BODY(i); NODE_BODY(i + 2); }
    if (i < end) NODE_BODY(i);
#undef NODE_BODY

    lsn[w2][0][co] = h10; lsn[w2][0][co + 1] = h11;
    lsn[w2][1][co] = h20; lsn[w2][1][co + 1] = h21;
    if (lane == 0) lnc[w2] = c1;
  }

  __syncthreads();
  if (w != 0) return;

  // ---- wave 0: combine + epilogue ----
  float ais0 = lse[0][0][co] + lse[1][0][co], ais1 = lse[0][0][co + 1] + lse[1][0][co + 1];
  float aos0 = lse[0][1][co] + lse[1][1][co], aos1 = lse[0][1][co + 1] + lse[1][1][co + 1];
  float ail0 = lse[0][2][co] + lse[1][2][co], ail1 = lse[0][2][co + 1] + lse[1][2][co + 1];
  float aol0 = lse[0][3][co] + lse[1][3][co], aol1 = lse[0][3][co + 1] + lse[1][3][co + 1];
  float hs0  = lse[0][4][co] + lse[1][4][co], hs1  = lse[0][4][co + 1] + lse[1][4][co + 1];
  float hl0  = lse[0][5][co] + lse[1][5][co], hl1  = lse[0][5][co + 1] + lse[1][5][co + 1];
  float h10  = lsn[0][0][co] + lsn[1][0][co], h11  = lsn[0][0][co + 1] + lsn[1][0][co + 1];
  float h20  = lsn[0][1][co] + lsn[1][1][co], h21  = lsn[0][1][co + 1] + lsn[1][1][co + 1];
  float d_is = lss[0][0] + lss[1][0];
  float d_os = lss[0][1] + lss[1][1];
  float d_il = lss[0][2] + lss[1][2];
  float d_ol = lss[0][3] + lss[1][3];
  float tsum = lss[0][4] + lss[1][4];
  float cin  = lss[0][5] + lss[1][5];
  float c1   = lnc[0] + lnc[1];
  float c2 = (float)nc - c1;

  float r_is = 1.0f / fmaxf(d_is, 1e-6f);
  float r_os = 1.0f / fmaxf(d_os, 1e-6f);
  float r_il = 1.0f / fmaxf(d_il, 1e-6f);
  float r_ol = 1.0f / fmaxf(d_ol, 1e-6f);
  float sm = d_is + d_os;
  float lm = d_il + d_ol;
  float r_sm = 1.0f / fmaxf(sm, 1e-6f);
  float r_lm = 1.0f / fmaxf(lm, 1e-6f);
  float r_c1 = 1.0f / fmaxf(c1, 1e-6f);
  float r_c2 = 1.0f / fmaxf(c2, 1e-6f);

  float mis0 = ais0 * r_is, mis1 = ais1 * r_is;
  float mos0 = aos0 * r_os, mos1 = aos1 * r_os;
  float mil0 = ail0 * r_il, mil1 = ail1 * r_il;
  float mol0 = aol0 * r_ol, mol1 = aol1 * r_ol;
  float mhs0 = hs0 * r_sm, mhs1 = hs1 * r_sm;
  float mhl0 = hl0 * r_lm, mhl1 = hl1 * r_lm;
  float mh10 = h10 * r_c1, mh11 = h11 * r_c1;
  float mh20 = h20 * r_c2, mh21 = h21 * r_c2;

  LN2 z_burst = ln128(mis0 + mos0 - mil0 - mol0, mis1 + mos1 - mil1 - mol1);
  LN2 z_dgap  = ln128(mol0 - mil0, mol1 - mil1);
  LN2 z_hgap  = ln128(mh10 - mh20, mh11 - mh21);
  LN2 z_sl    = ln128(mhs0 - mhl0, mhs1 - mhl1);
  LN2 z_asym  = ln128(fabsf(z_dgap.zx), fabsf(z_dgap.zy));
  LN2 z_h1    = ln128(mh10, mh11);
  LN2 z_h2    = ln128(mh20, mh21);
  LN2 z_rb    = ln128(mil0 + mol0, mil1 + mol1);

  if (lane == 0) {
    atomicAdd(&norm_acc[0], z_hgap.norm);
    atomicAdd(&norm_acc[1], z_sl.norm);
    atomicAdd(&norm_acc[2], z_dgap.norm);
  }

  float* frow = fused + (size_t)t * 1056;
  *(float2*)(frow + 0 * HDIM + co) = make_float2(z_burst.zx, z_burst.zy);
  *(float2*)(frow + 1 * HDIM + co) = make_float2(z_dgap.zx, z_dgap.zy);
  *(float2*)(frow + 2 * HDIM + co) = make_float2(z_hgap.zx, z_hgap.zy);
  *(float2*)(frow + 3 * HDIM + co) = make_float2(z_sl.zx, z_sl.zy);
  *(float2*)(frow + 4 * HDIM + co) = make_float2(z_asym.zx, z_asym.zy);
  *(float2*)(frow + 5 * HDIM + co) = make_float2(z_h1.zx, z_h1.zy);
  *(float2*)(frow + 6 * HDIM + co) = make_float2(z_h2.zx, z_h2.zy);
  *(float2*)(frow + 7 * HDIM + co) = make_float2(z_rb.zx, z_rb.zy);

  float ecf = (float)ec;
  float sf[8];
  sf[0] = log1pf(cin);
  sf[1] = log1pf(ecf - cin);
  sf[2] = log1pf(c1);
  sf[3] = log1pf(c2);
  sf[4] = tsum / fmaxf(ecf, 1e-6f);
  sf[5] = sm;
  sf[6] = lm;
  sf[7] = sm - lm;
  if (lane < 32) {
    float acc = b1[lane];
#pragma unroll
    for (int i = 0; i < 8; i++) acc += sf[i] * W1[i * 32 + lane];
    frow[1024 + lane] = gelu_exact(acc);
  }
}

// ---------------------------------------------------------------------------
// K5/K6: tiled fp32 GEMM  C[M,N] = epilogue(A[M,K] @ B[K,N] + bias)
// 32x64 tile, BK=32, 256 threads, 2x4 per-thread microtile.
// MODE 0: exact GELU. MODE 1: 0.25*tanh.
// M % 32 == 0, N % 64 == 0, K % 32 == 0 for our shapes.
// ---------------------------------------------------------------------------
template <int MODE>
__global__ __launch_bounds__(256) void gemm_kernel(
    const float* __restrict__ A, const float* __restrict__ B,
    const float* __restrict__ bias, float* __restrict__ C,
    int M, int N, int K) {
  __shared__ __align__(16) float As[32][34];  // [k][m]
  __shared__ __align__(16) float Bs[32][68];  // [k][n]
  const int tid = threadIdx.x;
  const int tx = tid & 15, ty = tid >> 4;
  const int m0 = blockIdx.y * 32, n0 = blockIdx.x * 64;
  float acc[2][4] = {};

  const int am = tid >> 3;            // 0..31
  const int ak = (tid & 7) * 4;       // 0,4,..,28
  const int bk = tid >> 3;            // 0..31
  const int bn = (tid & 7) * 8;       // 0,8,..,56

  for (int kt = 0; kt < K; kt += 32) {
    float4 av = *(const float4*)&A[(size_t)(m0 + am) * K + kt + ak];
    const float* bp = &B[(size_t)(kt + bk) * N + n0 + bn];
    float4 bv0 = *(const float4*)bp;
    float4 bv1 = *(const float4*)(bp + 4);
    As[ak + 0][am] = av.x;
    As[ak + 1][am] = av.y;
    As[ak + 2][am] = av.z;
    As[ak + 3][am] = av.w;
    *(float4*)&Bs[bk][bn] = bv0;
    *(float4*)&Bs[bk][bn + 4] = bv1;
    __syncthreads();
#pragma unroll
    for (int kk = 0; kk < 32; kk++) {
      float2 a2 = *(const float2*)&As[kk][ty * 2];
      float4 b4 = *(const float4*)&Bs[kk][tx * 4];
      float a[2] = {a2.x, a2.y};
      float b[4] = {b4.x, b4.y, b4.z, b4.w};
#pragma unroll
      for (int i2 = 0; i2 < 2; i2++)
#pragma unroll
        for (int j2 = 0; j2 < 4; j2++)
          acc[i2][j2] = fmaf(a[i2], b[j2], acc[i2][j2]);
    }
    __syncthreads();
  }

#pragma unroll
  for (int i2 = 0; i2 < 2; i2++) {
    int m = m0 + ty * 2 + i2;
    int n = n0 + tx * 4;
    float4 bb = *(const float4*)&bias[n];
    float4 v;
    v.x = acc[i2][0] + bb.x;
    v.y = acc[i2][1] + bb.y;
    v.z = acc[i2][2] + bb.z;
    v.w = acc[i2][3] + bb.w;
    if (MODE == 0) {
      v.x = gelu_exact(v.x); v.y = gelu_exact(v.y);
      v.z = gelu_exact(v.z); v.w = gelu_exact(v.w);
    } else {
      v.x = 0.25f * tanhf(v.x); v.y = 0.25f * tanhf(v.y);
      v.z = 0.25f * tanhf(v.z); v.w = 0.25f * tanhf(v.w);
    }
    *(float4*)&C[(size_t)m * N + n] = v;
  }
}

// ---------------------------------------------------------------------------
// K7: norms -> output tail
// ---------------------------------------------------------------------------
__global__ void finalize_kernel(const float* __restrict__ norm_acc,
                                float* __restrict__ out) {
  int i = threadIdx.x;
  if (i < 3) out[(size_t)TDIM * HDIM + i] = norm_acc[i] * (1.0f / (float)TDIM);
}

// ---------------------------------------------------------------------------
extern "C" void kernel_launch(void* const* d_in, const int* in_sizes, int n_in,
                              void* d_out, int out_size, void* d_ws, size_t ws_size,
                              hipStream_t stream) {
  const float* node_repr = (const float*)d_in[0];
  const float* edge_repr = (const float*)d_in[1];
  const int* edge_src = (const int*)d_in[2];
  const int* edge_dst = (const int*)d_in[3];
  const int* rel_ids = (const int*)d_in[4];
  const float* etime = (const float*)d_in[5];
  const int* tli = (const int*)d_in[6];
  const int* nsg = (const int*)d_in[7];
  const int* esg = (const int*)d_in[8];
  const int* depth = (const int*)d_in[9];
  const float* W1 = (const float*)d_in[10];
  const float* b1 = (const float*)d_in[11];
  const float* W2 = (const float*)d_in[12];
  const float* b2 = (const float*)d_in[13];
  const float* W3 = (const float*)d_in[14];
  const float* b3 = (const float*)d_in[15];
  float* out = (float*)d_out;

  const int E_ = in_sizes[2];
  const int N_ = in_sizes[7];

  char* ws = (char*)d_ws;
  size_t off = 0;
  auto alloc = [&](size_t bytes) -> void* {
    off = (off + 255) & ~(size_t)255;
    void* p = ws + off;
    off += bytes;
    return p;
  };
  int* ecnt = (int*)alloc((size_t)TDIM * 4);
  int* eoff = (int*)alloc((size_t)TDIM * 4);
  int* ecur = (int*)alloc((size_t)TDIM * 4);
  int* ncnt = (int*)alloc((size_t)TDIM * 4);
  int* noff = (int*)alloc((size_t)TDIM * 4);
  int* ncur = (int*)alloc((size_t)TDIM * 4);
  int* s_eid = (int*)alloc((size_t)E_ * 4);
  int* s_srcpk = (int*)alloc((size_t)E_ * 4);
  float* s_t = (float*)alloc((size_t)E_ * 4);
  int* s_npk = (int*)alloc((size_t)N_ * 4);
  float* fused = (float*)alloc((size_t)TDIM * 1056 * 4);
  float* hidden = (float*)alloc((size_t)TDIM * 256 * 4);
  float* norm_acc = (float*)alloc(4 * 4);

  hipMemsetAsync(ecnt, 0, (size_t)TDIM * 4, stream);
  hipMemsetAsync(ncnt, 0, (size_t)TDIM * 4, stream);
  hipMemsetAsync(norm_acc, 0, 16, stream);

  int gmax = (E_ > N_ ? E_ : N_);
  int g1 = (gmax + 255) / 256;

  count_kernel<<<g1, 256, 0, stream>>>(edge_dst, esg, tli, nsg, ecnt, ncnt, E_, N_);
  scan_kernel<<<2, 64, 0, stream>>>(ecnt, eoff, ecur, ncnt, noff, ncur);
  scatter_kernel<<<g1, 256, 0, stream>>>(edge_dst, esg, tli, edge_src, rel_ids,
                                         etime, nsg, depth, ecur, ncur,
                                         s_eid, s_srcpk, s_t, s_npk, E_, N_);
  target_kernel<<<TDIM, 256, 0, stream>>>(node_repr, edge_repr, eoff, ecnt, noff,
                                          ncnt, s_eid, s_srcpk, s_t, s_npk,
                                          W1, b1, fused, norm_acc);
  gemm_kernel<0><<<dim3(256 / 64, TDIM / 32), 256, 0, stream>>>(
      fused, W2, b2, hidden, TDIM, 256, 8 * HDIM + 32);
  gemm_kernel<1><<<dim3(HDIM / 64, TDIM / 32), 256, 0, stream>>>(
      hidden, W3, b3, out, TDIM, HDIM, 256);
  finalize_kernel<<<1, 64, 0, stream>>>(norm_acc, out);
}